// Round 1
// baseline (1424.449 us; speedup 1.0000x reference)
//
#include <hip/hip_runtime.h>

#define N_NODES 100000
#define N_EDGES 1600000
#define D 64
#define EPS 1e-5f

// ---------------- workspace layout (byte offsets) ----------------
// flag    @ 0          (256 B)
// deg     @ 256        (N*4)
// dinv    @ 400256     (N*4)
// off     @ 800256     ((N+1)*4, padded to 400064)
// bsum    @ 1200320    (512)
// cursor  @ 1200832    (N*4)
// stats   @ 1600832    (512, padded to 1601536)
// packed  @ 1601536    (E*8)
// h       @ 14401536   (N*64*4)
// agg     @ 40001536   (N*64*4)
// xbuf    @ 65601536   (N*64*4)
// total ~91.2 MB

#define SCAN_BLOCKS 128
#define SCAN_T 256

// Detect whether edge_index is int64 (odd 32-bit words are all-zero high
// halves) or int32 (odd words are random node ids). flag=1 -> int64.
__global__ void detect_kernel(const unsigned* __restrict__ ei, int* __restrict__ flag) {
    int t = threadIdx.x;
    unsigned stride = (2u * (unsigned)N_EDGES) / 256u;  // 12500 (even)
    unsigned w = (unsigned)t * stride + 1u;             // odd index
    unsigned v = ei[w];
    __shared__ unsigned red[256];
    red[t] = v;
    __syncthreads();
    for (int s = 128; s > 0; s >>= 1) {
        if (t < s) red[t] |= red[t + s];
        __syncthreads();
    }
    if (t == 0) *flag = (red[0] == 0u) ? 1 : 0;
}

__device__ __forceinline__ int load_idx(const void* ei, int is64, size_t pos) {
    if (is64) return (int)((const long long*)ei)[pos];
    return ((const int*)ei)[pos];
}

__global__ void degcount_kernel(const void* __restrict__ ei, const int* __restrict__ flag,
                                float* __restrict__ deg) {
    int e = blockIdx.x * 256 + threadIdx.x;
    if (e >= N_EDGES) return;
    int is64 = *flag;
    int d = load_idx(ei, is64, (size_t)N_EDGES + e);
    atomicAdd(&deg[d], 1.0f);
}

__global__ void dinv_kernel(const float* __restrict__ deg, float* __restrict__ dinv) {
    int n = blockIdx.x * 256 + threadIdx.x;
    if (n >= N_NODES) return;
    dinv[n] = rsqrtf(deg[n] + 1.0f);
}

__global__ void scanA_kernel(const float* __restrict__ deg, int* __restrict__ bsum) {
    int b = blockIdx.x, t = threadIdx.x;
    const int chunk = (N_NODES + SCAN_BLOCKS - 1) / SCAN_BLOCKS;  // 782
    const int tchunk = (chunk + SCAN_T - 1) / SCAN_T;             // 4
    int lo = b * chunk + t * tchunk;
    int hi = min(lo + tchunk, min((b + 1) * chunk, N_NODES));
    int s = 0;
    for (int i = lo; i < hi; ++i) s += (int)deg[i];
    __shared__ int red[SCAN_T];
    red[t] = s;
    __syncthreads();
    for (int st = 128; st > 0; st >>= 1) {
        if (t < st) red[t] += red[t + st];
        __syncthreads();
    }
    if (t == 0) bsum[b] = red[0];
}

__global__ void scanB_kernel(int* __restrict__ bsum) {
    __shared__ int sh[SCAN_BLOCKS];
    int t = threadIdx.x;
    sh[t] = bsum[t];
    __syncthreads();
    for (int st = 1; st < SCAN_BLOCKS; st <<= 1) {
        int v = (t >= st) ? sh[t - st] : 0;
        __syncthreads();
        sh[t] += v;
        __syncthreads();
    }
    bsum[t] = (t == 0) ? 0 : sh[t - 1];  // exclusive
}

__global__ void scanC_kernel(const float* __restrict__ deg, const int* __restrict__ bsum,
                             int* __restrict__ off, int* __restrict__ cursor) {
    int b = blockIdx.x, t = threadIdx.x;
    const int chunk = (N_NODES + SCAN_BLOCKS - 1) / SCAN_BLOCKS;
    const int tchunk = (chunk + SCAN_T - 1) / SCAN_T;
    int lo = b * chunk + t * tchunk;
    int hi = min(lo + tchunk, min((b + 1) * chunk, N_NODES));
    int s = 0;
    for (int i = lo; i < hi; ++i) s += (int)deg[i];
    __shared__ int red[SCAN_T];
    red[t] = s;
    __syncthreads();
    for (int st = 1; st < SCAN_T; st <<= 1) {
        int v = (t >= st) ? red[t - st] : 0;
        __syncthreads();
        red[t] += v;
        __syncthreads();
    }
    int tbase = bsum[b] + red[t] - s;  // exclusive prefix for this thread
    for (int i = lo; i < hi; ++i) {
        int d = (int)deg[i];
        off[i] = tbase;
        cursor[i] = tbase;
        tbase += d;
    }
    if (b == 0 && t == 0) off[N_NODES] = N_EDGES;
}

__global__ void bucket_kernel(const void* __restrict__ ei, const int* __restrict__ flag,
                              const float* __restrict__ dinv, int* __restrict__ cursor,
                              long long* __restrict__ packed) {
    int e = blockIdx.x * 256 + threadIdx.x;
    if (e >= N_EDGES) return;
    int is64 = *flag;
    int s = load_idx(ei, is64, e);
    int d = load_idx(ei, is64, (size_t)N_EDGES + e);
    int pos = atomicAdd(&cursor[d], 1);
    unsigned long long pk =
        (unsigned long long)(unsigned)s |
        ((unsigned long long)__float_as_uint(dinv[s]) << 32);
    packed[pos] = (long long)pk;
}

// h = x @ W.  One wave per row: lane = output column, W column held in 64 VGPRs,
// x-row reads are (wave-)uniform-address -> served as broadcast 16B transactions.
__global__ __launch_bounds__(256) void gemm_kernel(const float* __restrict__ x,
                                                   const float* __restrict__ W,
                                                   float* __restrict__ h) {
    int lane = threadIdx.x & 63;
    int wv = threadIdx.x >> 6;
    float wcol[64];
#pragma unroll
    for (int k = 0; k < 64; ++k) wcol[k] = W[k * 64 + lane];
    int row0 = blockIdx.x * 64;
    for (int r = wv; r < 64; r += 4) {
        int row = row0 + r;
        if (row >= N_NODES) break;
        const float* xr = x + (size_t)row * 64;
        float acc = 0.f;
#pragma unroll
        for (int k = 0; k < 64; ++k) acc += xr[k] * wcol[k];
        h[(size_t)row * 64 + lane] = acc;
    }
}

// agg[n] = dinv[n]^2 * h[n] + b + sum_{e: dst=n} dinv[src]*dinv[n]*h[src]
// One wave per node; edge-list reads wave-uniform; h-row reads 256B coalesced.
__global__ __launch_bounds__(256) void gather_kernel(const float* __restrict__ h,
                                                     const int* __restrict__ off,
                                                     const long long* __restrict__ packed,
                                                     const float* __restrict__ dinv,
                                                     const float* __restrict__ b,
                                                     float* __restrict__ agg) {
    int lane = threadIdx.x & 63;
    int wv = threadIdx.x >> 6;
    int n = blockIdx.x * 4 + wv;
    if (n >= N_NODES) return;
    float dn = dinv[n];
    float acc = dn * dn * h[(size_t)n * 64 + lane] + b[lane];
    int j0 = off[n], j1 = off[n + 1];
    for (int j = j0; j < j1; ++j) {
        long long pk = packed[j];
        int s = (int)(pk & 0xffffffffLL);
        float ds = __int_as_float((int)(pk >> 32));
        acc += (ds * dn) * h[(size_t)s * 64 + lane];
    }
    agg[(size_t)n * 64 + lane] = acc;
}

// Column sums / sum-of-squares of relu(agg) -> stats[0:64], stats[64:128].
__global__ __launch_bounds__(256) void stats_kernel(const float* __restrict__ agg,
                                                    float* __restrict__ stats) {
    int lane = threadIdx.x & 63;
    int sub = threadIdx.x >> 6;
    float s1 = 0.f, s2 = 0.f;
    for (int r = blockIdx.x * 4 + sub; r < N_NODES; r += gridDim.x * 4) {
        float v = agg[(size_t)r * 64 + lane];
        v = fmaxf(v, 0.f);
        s1 += v;
        s2 += v * v;
    }
    __shared__ float red[2][4][64];
    red[0][sub][lane] = s1;
    red[1][sub][lane] = s2;
    __syncthreads();
    if (sub == 0) {
        s1 = red[0][0][lane] + red[0][1][lane] + red[0][2][lane] + red[0][3][lane];
        s2 = red[1][0][lane] + red[1][1][lane] + red[1][2][lane] + red[1][3][lane];
        atomicAdd(&stats[lane], s1);
        atomicAdd(&stats[64 + lane], s2);
    }
}

// out = gamma * (relu(agg) - mean) * rsqrt(var + eps) + beta   (float4 vectorized)
__global__ __launch_bounds__(256) void apply_kernel(const float* __restrict__ agg,
                                                    const float* __restrict__ stats,
                                                    const float* __restrict__ gamma,
                                                    const float* __restrict__ beta,
                                                    float* __restrict__ out) {
    int i = blockIdx.x * 256 + threadIdx.x;
    if (i >= N_NODES * 16) return;
    int d0 = (i & 15) << 2;
    float4 v = reinterpret_cast<const float4*>(agg)[i];
    float r[4] = {v.x, v.y, v.z, v.w};
    float4 o;
    float* op = &o.x;
    const float invN = 1.0f / (float)N_NODES;
#pragma unroll
    for (int j = 0; j < 4; ++j) {
        int d = d0 + j;
        float mean = stats[d] * invN;
        float var = stats[64 + d] * invN - mean * mean;
        float rs = rsqrtf(var + EPS);
        float val = fmaxf(r[j], 0.f);
        op[j] = gamma[d] * (val - mean) * rs + beta[d];
    }
    reinterpret_cast<float4*>(out)[i] = o;
}

extern "C" void kernel_launch(void* const* d_in, const int* in_sizes, int n_in,
                              void* d_out, int out_size, void* d_ws, size_t ws_size,
                              hipStream_t stream) {
    const void* ei = d_in[0];
    const float* node_attr = (const float*)d_in[1];
    // d_in[2] = edge_attr (unused by the reference)

    char* ws = (char*)d_ws;
    int* flag = (int*)(ws + 0);
    float* deg = (float*)(ws + 256);
    float* dinv = (float*)(ws + 400256);
    int* off = (int*)(ws + 800256);
    int* bsum = (int*)(ws + 1200320);
    int* cursor = (int*)(ws + 1200832);
    float* stats = (float*)(ws + 1600832);
    long long* packed = (long long*)(ws + 1601536);
    float* h = (float*)(ws + 14401536);
    float* agg = (float*)(ws + 40001536);
    float* xbuf = (float*)(ws + 65601536);

    hipMemsetAsync(deg, 0, (size_t)N_NODES * 4, stream);
    detect_kernel<<<1, 256, 0, stream>>>((const unsigned*)ei, flag);
    degcount_kernel<<<N_EDGES / 256, 256, 0, stream>>>(ei, flag, deg);
    dinv_kernel<<<(N_NODES + 255) / 256, 256, 0, stream>>>(deg, dinv);
    scanA_kernel<<<SCAN_BLOCKS, SCAN_T, 0, stream>>>(deg, bsum);
    scanB_kernel<<<1, SCAN_BLOCKS, 0, stream>>>(bsum);
    scanC_kernel<<<SCAN_BLOCKS, SCAN_T, 0, stream>>>(deg, bsum, off, cursor);
    bucket_kernel<<<N_EDGES / 256, 256, 0, stream>>>(ei, flag, dinv, cursor, packed);

    const float* x = node_attr;
    for (int l = 0; l < 3; ++l) {
        const float* W = (const float*)d_in[3 + 4 * l];
        const float* b = (const float*)d_in[4 + 4 * l];
        const float* gamma = (const float*)d_in[5 + 4 * l];
        const float* beta = (const float*)d_in[6 + 4 * l];

        gemm_kernel<<<(N_NODES + 63) / 64, 256, 0, stream>>>(x, W, h);
        gather_kernel<<<(N_NODES + 3) / 4, 256, 0, stream>>>(h, off, packed, dinv, b, agg);
        hipMemsetAsync(stats, 0, 512, stream);
        stats_kernel<<<1024, 256, 0, stream>>>(agg, stats);
        float* outp = (l == 2) ? (float*)d_out : xbuf;
        apply_kernel<<<(N_NODES * 16 + 255) / 256, 256, 0, stream>>>(agg, stats, gamma, beta, outp);
        x = xbuf;
    }
}

// Round 2
// 1169.428 us; speedup vs baseline: 1.2181x; 1.2181x over previous
//
#include <hip/hip_runtime.h>

#define N_NODES 100000
#define N_EDGES 1600000
#define D 64
#define EPS 1e-5f

// ---------------- workspace layout (byte offsets, all 16B-aligned) ----------
// flag    @ 0          (256 B)
// deg     @ 256        (N*4)
// dinv    @ 400256     (N*4)
// off     @ 800256     ((N+1)*4, pad to 400128)
// bsum    @ 1200384    (512)
// cursor  @ 1200896    (N*4)
// stats   @ 1600896    (3 layers * 128 floats = 1536 B)
// packed  @ 1602432    (E*8)
// h       @ 14402432   (N*64*4)
// agg     @ 40002432   (N*64*4)
// xbuf    @ 65602432   (N*64*4)  -> end 91202432 (~91 MB)

#define SCAN_BLOCKS 128
#define SCAN_T 256

// Zero deg + stats; last block also detects int64-vs-int32 edge_index layout
// (odd 32-bit words all-zero => int64 high halves => flag=1).
__global__ void setup_kernel(const unsigned* __restrict__ ei, int* __restrict__ flag,
                             int* __restrict__ deg, float* __restrict__ stats) {
    int t = blockIdx.x * 256 + threadIdx.x;
    if (t < N_NODES) deg[t] = 0;
    if (t < 384) stats[t] = 0.f;
    if (blockIdx.x == gridDim.x - 1) {
        int tt = threadIdx.x;
        unsigned stride = (2u * (unsigned)N_EDGES) / 256u;  // even
        unsigned v = ei[(unsigned)tt * stride + 1u];        // odd word
        __shared__ unsigned red[256];
        red[tt] = v;
        __syncthreads();
        for (int s = 128; s > 0; s >>= 1) {
            if (tt < s) red[tt] |= red[tt + s];
            __syncthreads();
        }
        if (tt == 0) *flag = (red[0] == 0u) ? 1 : 0;
    }
}

__device__ __forceinline__ int load_idx(const void* ei, int is64, size_t pos) {
    if (is64) return (int)((const long long*)ei)[pos];
    return ((const int*)ei)[pos];
}

__global__ void degcount_kernel(const void* __restrict__ ei, const int* __restrict__ flag,
                                int* __restrict__ deg) {
    int e = blockIdx.x * 256 + threadIdx.x;
    if (e >= N_EDGES) return;
    int is64 = *flag;
    int d = load_idx(ei, is64, (size_t)N_EDGES + e);
    atomicAdd(&deg[d], 1);
}

// Per-block degree sums (for the scan) + dinv = rsqrt(deg+1) fused in.
__global__ void scanA_kernel(const int* __restrict__ deg, float* __restrict__ dinv,
                             int* __restrict__ bsum) {
    int b = blockIdx.x, t = threadIdx.x;
    const int chunk = (N_NODES + SCAN_BLOCKS - 1) / SCAN_BLOCKS;  // 782
    const int tchunk = (chunk + SCAN_T - 1) / SCAN_T;             // 4
    int lo = b * chunk + t * tchunk;
    int hi = min(lo + tchunk, min((b + 1) * chunk, N_NODES));
    int s = 0;
    for (int i = lo; i < hi; ++i) {
        int d = deg[i];
        s += d;
        dinv[i] = rsqrtf((float)d + 1.0f);
    }
    __shared__ int red[SCAN_T];
    red[t] = s;
    __syncthreads();
    for (int st = 128; st > 0; st >>= 1) {
        if (t < st) red[t] += red[t + st];
        __syncthreads();
    }
    if (t == 0) bsum[b] = red[0];
}

__global__ void scanB_kernel(int* __restrict__ bsum) {
    __shared__ int sh[SCAN_BLOCKS];
    int t = threadIdx.x;
    sh[t] = bsum[t];
    __syncthreads();
    for (int st = 1; st < SCAN_BLOCKS; st <<= 1) {
        int v = (t >= st) ? sh[t - st] : 0;
        __syncthreads();
        sh[t] += v;
        __syncthreads();
    }
    bsum[t] = (t == 0) ? 0 : sh[t - 1];  // exclusive
}

__global__ void scanC_kernel(const int* __restrict__ deg, const int* __restrict__ bsum,
                             int* __restrict__ off, int* __restrict__ cursor) {
    int b = blockIdx.x, t = threadIdx.x;
    const int chunk = (N_NODES + SCAN_BLOCKS - 1) / SCAN_BLOCKS;
    const int tchunk = (chunk + SCAN_T - 1) / SCAN_T;
    int lo = b * chunk + t * tchunk;
    int hi = min(lo + tchunk, min((b + 1) * chunk, N_NODES));
    int s = 0;
    for (int i = lo; i < hi; ++i) s += deg[i];
    __shared__ int red[SCAN_T];
    red[t] = s;
    __syncthreads();
    for (int st = 1; st < SCAN_T; st <<= 1) {
        int v = (t >= st) ? red[t - st] : 0;
        __syncthreads();
        red[t] += v;
        __syncthreads();
    }
    int tbase = bsum[b] + red[t] - s;  // exclusive prefix for this thread
    for (int i = lo; i < hi; ++i) {
        int d = deg[i];
        off[i] = tbase;
        cursor[i] = tbase;
        tbase += d;
    }
    if (b == 0 && t == 0) off[N_NODES] = N_EDGES;
}

__global__ void bucket_kernel(const void* __restrict__ ei, const int* __restrict__ flag,
                              const float* __restrict__ dinv, int* __restrict__ cursor,
                              long long* __restrict__ packed) {
    int e = blockIdx.x * 256 + threadIdx.x;
    if (e >= N_EDGES) return;
    int is64 = *flag;
    int s = load_idx(ei, is64, e);
    int d = load_idx(ei, is64, (size_t)N_EDGES + e);
    int pos = atomicAdd(&cursor[d], 1);
    unsigned long long pk =
        (unsigned long long)(unsigned)s |
        ((unsigned long long)__float_as_uint(dinv[s]) << 32);
    __builtin_nontemporal_store((long long)pk, &packed[pos]);
}

// h = x @ W.  One wave per row: lane = output column, W column in 64 VGPRs,
// x-row reads wave-uniform (broadcast).
__global__ __launch_bounds__(256) void gemm_kernel(const float* __restrict__ x,
                                                   const float* __restrict__ W,
                                                   float* __restrict__ h) {
    int lane = threadIdx.x & 63;
    int wv = threadIdx.x >> 6;
    float wcol[64];
#pragma unroll
    for (int k = 0; k < 64; ++k) wcol[k] = W[k * 64 + lane];
    int row0 = blockIdx.x * 64;
    for (int r = wv; r < 64; r += 4) {
        int row = row0 + r;
        if (row >= N_NODES) break;
        const float* xr = x + (size_t)row * 64;
        float acc = 0.f;
#pragma unroll
        for (int k = 0; k < 64; ++k) acc += xr[k] * wcol[k];
        h[(size_t)row * 64 + lane] = acc;
    }
}

// agg[n] = dinv[n]^2 * h[n] + b + sum_{e: dst=n} dinv[src]*dinv[n]*h[src]
// Wave per node; 4 lane-groups process 4 edges concurrently, each lane holds a
// float4 feature-quad -> 4x memory-level parallelism vs one-edge-per-iteration.
__global__ __launch_bounds__(256) void gather_kernel(const float* __restrict__ h,
                                                     const int* __restrict__ off,
                                                     const long long* __restrict__ packed,
                                                     const float* __restrict__ dinv,
                                                     const float* __restrict__ b,
                                                     float* __restrict__ agg) {
    int lane = threadIdx.x & 63;
    int wv = threadIdx.x >> 6;
    int n = blockIdx.x * 4 + wv;
    if (n >= N_NODES) return;
    int g = lane >> 4;    // edge sub-group 0..3
    int fq = lane & 15;   // feature quad: features 4*fq .. 4*fq+3
    float dn = dinv[n];
    float4 acc = make_float4(0.f, 0.f, 0.f, 0.f);
    int j0 = off[n], j1 = off[n + 1];
    for (int j = j0; j < j1; j += 4) {
        int jj = j + g;
        if (jj < j1) {
            long long pk = packed[jj];
            int s = (int)(pk & 0xffffffffLL);
            float w = __int_as_float((int)(pk >> 32)) * dn;
            float4 hv = reinterpret_cast<const float4*>(h + (size_t)s * 64)[fq];
            acc.x += w * hv.x;
            acc.y += w * hv.y;
            acc.z += w * hv.z;
            acc.w += w * hv.w;
        }
    }
    // reduce the 4 edge sub-groups (lanes differing in bits 4 and 5)
#pragma unroll
    for (int m = 16; m <= 32; m <<= 1) {
        acc.x += __shfl_xor(acc.x, m, 64);
        acc.y += __shfl_xor(acc.y, m, 64);
        acc.z += __shfl_xor(acc.z, m, 64);
        acc.w += __shfl_xor(acc.w, m, 64);
    }
    if (g == 0) {
        float4 hv = reinterpret_cast<const float4*>(h + (size_t)n * 64)[fq];
        float4 bv = reinterpret_cast<const float4*>(b)[fq];
        float sw = dn * dn;
        float4 o;
        o.x = acc.x + sw * hv.x + bv.x;
        o.y = acc.y + sw * hv.y + bv.y;
        o.z = acc.z + sw * hv.z + bv.z;
        o.w = acc.w + sw * hv.w + bv.w;
        reinterpret_cast<float4*>(agg + (size_t)n * 64)[fq] = o;
    }
}

// Column sums / sum-of-squares of relu(agg) -> stats[0:64], stats[64:128].
__global__ __launch_bounds__(256) void stats_kernel(const float* __restrict__ agg,
                                                    float* __restrict__ stats) {
    int lane = threadIdx.x & 63;
    int sub = threadIdx.x >> 6;
    float s1 = 0.f, s2 = 0.f;
    for (int r = blockIdx.x * 4 + sub; r < N_NODES; r += gridDim.x * 4) {
        float v = agg[(size_t)r * 64 + lane];
        v = fmaxf(v, 0.f);
        s1 += v;
        s2 += v * v;
    }
    __shared__ float red[2][4][64];
    red[0][sub][lane] = s1;
    red[1][sub][lane] = s2;
    __syncthreads();
    if (sub == 0) {
        s1 = red[0][0][lane] + red[0][1][lane] + red[0][2][lane] + red[0][3][lane];
        s2 = red[1][0][lane] + red[1][1][lane] + red[1][2][lane] + red[1][3][lane];
        atomicAdd(&stats[lane], s1);
        atomicAdd(&stats[64 + lane], s2);
    }
}

// out = gamma * (relu(agg) - mean) * rsqrt(var + eps) + beta   (float4)
__global__ __launch_bounds__(256) void apply_kernel(const float* __restrict__ agg,
                                                    const float* __restrict__ stats,
                                                    const float* __restrict__ gamma,
                                                    const float* __restrict__ beta,
                                                    float* __restrict__ out) {
    int i = blockIdx.x * 256 + threadIdx.x;
    if (i >= N_NODES * 16) return;
    int d0 = (i & 15) << 2;
    float4 v = reinterpret_cast<const float4*>(agg)[i];
    float r[4] = {v.x, v.y, v.z, v.w};
    float4 o;
    float* op = &o.x;
    const float invN = 1.0f / (float)N_NODES;
#pragma unroll
    for (int j = 0; j < 4; ++j) {
        int d = d0 + j;
        float mean = stats[d] * invN;
        float var = stats[64 + d] * invN - mean * mean;
        float rs = rsqrtf(var + EPS);
        float val = fmaxf(r[j], 0.f);
        op[j] = gamma[d] * (val - mean) * rs + beta[d];
    }
    reinterpret_cast<float4*>(out)[i] = o;
}

extern "C" void kernel_launch(void* const* d_in, const int* in_sizes, int n_in,
                              void* d_out, int out_size, void* d_ws, size_t ws_size,
                              hipStream_t stream) {
    const void* ei = d_in[0];
    const float* node_attr = (const float*)d_in[1];
    // d_in[2] = edge_attr (unused by the reference)

    char* ws = (char*)d_ws;
    int* flag = (int*)(ws + 0);
    int* deg = (int*)(ws + 256);
    float* dinv = (float*)(ws + 400256);
    int* off = (int*)(ws + 800256);
    int* bsum = (int*)(ws + 1200384);
    int* cursor = (int*)(ws + 1200896);
    float* stats = (float*)(ws + 1600896);
    long long* packed = (long long*)(ws + 1602432);
    float* h = (float*)(ws + 14402432);
    float* agg = (float*)(ws + 40002432);
    float* xbuf = (float*)(ws + 65602432);

    setup_kernel<<<(N_NODES + 255) / 256, 256, 0, stream>>>((const unsigned*)ei, flag, deg, stats);
    degcount_kernel<<<N_EDGES / 256, 256, 0, stream>>>(ei, flag, deg);
    scanA_kernel<<<SCAN_BLOCKS, SCAN_T, 0, stream>>>(deg, dinv, bsum);
    scanB_kernel<<<1, SCAN_BLOCKS, 0, stream>>>(bsum);
    scanC_kernel<<<SCAN_BLOCKS, SCAN_T, 0, stream>>>(deg, bsum, off, cursor);
    bucket_kernel<<<N_EDGES / 256, 256, 0, stream>>>(ei, flag, dinv, cursor, packed);

    const float* x = node_attr;
    for (int l = 0; l < 3; ++l) {
        const float* W = (const float*)d_in[3 + 4 * l];
        const float* b = (const float*)d_in[4 + 4 * l];
        const float* gamma = (const float*)d_in[5 + 4 * l];
        const float* beta = (const float*)d_in[6 + 4 * l];
        float* stats_l = stats + 128 * l;

        gemm_kernel<<<(N_NODES + 63) / 64, 256, 0, stream>>>(x, W, h);
        gather_kernel<<<(N_NODES + 3) / 4, 256, 0, stream>>>(h, off, packed, dinv, b, agg);
        stats_kernel<<<1024, 256, 0, stream>>>(agg, stats_l);
        float* outp = (l == 2) ? (float*)d_out : xbuf;
        apply_kernel<<<(N_NODES * 16 + 255) / 256, 256, 0, stream>>>(agg, stats_l, gamma, beta, outp);
        x = xbuf;
    }
}